// Round 6
// baseline (635.346 us; speedup 1.0000x reference)
//
#include <hip/hip_runtime.h>
#include <stdint.h>

typedef float   f32x4  __attribute__((ext_vector_type(4)));
typedef float   f32x2  __attribute__((ext_vector_type(2)));
typedef __bf16  bf16x8 __attribute__((ext_vector_type(8)));
typedef __bf16  bf16x4 __attribute__((ext_vector_type(4)));
typedef uint32_t u32x4 __attribute__((ext_vector_type(4)));
typedef uint32_t u32x2 __attribute__((ext_vector_type(2)));

#define NN 8192
#define EMB 64
#define A_SCALE 8192.0f          // A*2^13 -> [0,1): e4m3 normal range
#define A_UNSCALE (1.0f/8192.0f)
#define SPLIT 8

__device__ inline float bf16lo_f(uint32_t u) {
  uint32_t b = u << 16; float f; __builtin_memcpy(&f, &b, 4); return f;
}
__device__ inline float bf16hi_f(uint32_t u) {
  uint32_t b = u & 0xFFFF0000u; float f; __builtin_memcpy(&f, &b, 4); return f;
}

// async global->LDS, 16B per lane. LDS dest is wave-uniform base + lane*16.
__device__ inline void gload16(const void* g, void* l) {
  __builtin_amdgcn_global_load_lds(
      (const __attribute__((address_space(1))) void*)g,
      (__attribute__((address_space(3))) void*)l, 16, 0, 0);
}

// ------- fused independent producers: quant(A->A8) ++ xw1(X@W1 -> XW1t) -------
// blocks [0,2048): streaming A fp32 -> fp8 tiled.  blocks [2048,3072): XW1^T.
__global__ __launch_bounds__(256) void k_qx(const float* __restrict__ A,
    unsigned char* __restrict__ A8, const float* __restrict__ X,
    const float* __restrict__ W1, __bf16* __restrict__ XW1t,
    float* __restrict__ rsum) {
  const int t = threadIdx.x;
  if (blockIdx.x < 2048) {
    const long stride = 2048L * 256;
    const long total = (long)NN * NN / 16;            // 16-float units
    for (long idx = (long)blockIdx.x * 256 + t; idx < total; idx += stride) {
      const long r = idx >> 9;                        // 512 units per row
      const int k0 = (int)(idx & 511) * 16;
      const f32x4* src = (const f32x4*)(A + r * NN + k0);
      u32x4 o;
#pragma unroll
      for (int i = 0; i < 4; ++i) {
        f32x4 v = src[i];
        int p8 = __builtin_amdgcn_cvt_pk_fp8_f32(v[0] * A_SCALE, v[1] * A_SCALE, 0, false);
        p8     = __builtin_amdgcn_cvt_pk_fp8_f32(v[2] * A_SCALE, v[3] * A_SCALE, p8, true);
        o[i] = (uint32_t)p8;
      }
      *(u32x4*)&A8[(long)(k0 >> 6) * ((long)NN * 64) + r * 64 + (k0 & 63)] = o;
    }
  } else {
    const int bid = blockIdx.x - 2048;
    if (bid < 32) rsum[bid * 256 + t] = 0.f;
    const int j = t & 127, r2 = t >> 7;
    const long row0 = (long)bid * 8 + r2 * 4;         // wave-uniform 4-row group
    const f32x4* xr = (const f32x4*)(X + row0 * 256);
    float a0 = 0.f, a1 = 0.f, a2 = 0.f, a3 = 0.f;
#pragma unroll 4
    for (int k4 = 0; k4 < 64; ++k4) {
      f32x4 x0 = xr[k4];
      f32x4 x1 = xr[k4 + 64];
      f32x4 x2 = xr[k4 + 128];
      f32x4 x3 = xr[k4 + 192];
#pragma unroll
      for (int u = 0; u < 4; ++u) {
        float wv = W1[(k4 * 4 + u) * 128 + j];
        a0 += x0[u] * wv;
        a1 += x1[u] * wv;
        a2 += x2[u] * wv;
        a3 += x3[u] * wv;
      }
    }
    bf16x4 ov;
    ov[0] = (__bf16)a0; ov[1] = (__bf16)a1; ov[2] = (__bf16)a2; ov[3] = (__bf16)a3;
    *(bf16x4*)&XW1t[(long)j * NN + row0] = ov;
  }
}

// ------- fused: reduce split-K bf16 partials -> relu -> (row @ W2) -> Yt bf16 ----
__global__ __launch_bounds__(256) void k_rely(const __bf16* __restrict__ hp,
    const float* __restrict__ W2, __bf16* __restrict__ Yt) {
  __shared__ float hrow[4][128];
  const uint32_t* hp32 = (const uint32_t*)hp;
  const int t = threadIdx.x, lane = t & 63, w = t >> 6;
  const long row = (long)blockIdx.x * 4 + w;    // one wave == one row
  const long b32 = row * 64;                    // 128 bf16 = 64 u32 per row
  float v0 = 0.f, v1 = 0.f;
#pragma unroll
  for (int sI = 0; sI < SPLIT; ++sI) {
    uint32_t u = hp32[b32 + lane + (long)sI * 524288];
    v0 += bf16lo_f(u);
    v1 += bf16hi_f(u);
  }
  hrow[w][2 * lane]     = fmaxf(v0, 0.f);
  hrow[w][2 * lane + 1] = fmaxf(v1, 0.f);
  __syncthreads();
  float a0 = 0.f, a1 = 0.f, a2 = 0.f, a3 = 0.f;
  const f32x4* hv = (const f32x4*)&hrow[w][0];
#pragma unroll 8
  for (int c4 = 0; c4 < 32; ++c4) {
    f32x4 h = hv[c4];
    a0 += h[0] * W2[(c4 * 4 + 0) * 64 + lane];
    a1 += h[1] * W2[(c4 * 4 + 1) * 64 + lane];
    a2 += h[2] * W2[(c4 * 4 + 2) * 64 + lane];
    a3 += h[3] * W2[(c4 * 4 + 3) * 64 + lane];
  }
  Yt[(long)lane * NN + row] = (__bf16)((a0 + a1) + (a2 + a3));
}

// ------- reduce epart (bf16, scaled by 2^13) -> emb bf16 + sq ----------------
__global__ __launch_bounds__(256) void k_reduce2(const __bf16* __restrict__ ep,
    __bf16* __restrict__ embb, float* __restrict__ sq) {
  const uint32_t* ep32 = (const uint32_t*)ep;
  const int t = threadIdx.x;
  const int hl = t & 31;                              // u32 index within row
  const long row = (long)blockIdx.x * 8 + (t >> 5);   // 8 rows per block
  const long idx = row * 32 + hl;                     // 64 bf16 = 32 u32 per row
  float v0 = 0.f, v1 = 0.f;
#pragma unroll
  for (int sI = 0; sI < SPLIT; ++sI) {
    uint32_t u = ep32[idx + (long)sI * 262144];
    v0 += bf16lo_f(u);
    v1 += bf16hi_f(u);
  }
  v0 *= A_UNSCALE; v1 *= A_UNSCALE;
  __bf16 b0 = (__bf16)v0, b1 = (__bf16)v1;
  unsigned short u0, u1;
  __builtin_memcpy(&u0, &b0, 2); __builtin_memcpy(&u1, &b1, 2);
  ((uint32_t*)embb)[idx] = ((uint32_t)u1 << 16) | u0;
  float f0 = (float)b0, f1 = (float)b1;
  float s = f0 * f0 + f1 * f1;
#pragma unroll
  for (int off = 16; off >= 1; off >>= 1) s += __shfl_xor(s, off);
  if (hl == 0) sq[row] = s;
}

// ------- gemm1: hpart[s] = A8tiled @ XW1t^T  (fp8 A dequant at read) -----------
// Operand-swapped MFMA: acc[nt][mt] rows = N-dim -> lane holds 4 consecutive
// output COLUMNS -> bf16x4 (8B) C-stores instead of 2B scalars.
__global__ __launch_bounds__(256, 3) void k_gemm1(const unsigned char* __restrict__ A8,
    const __bf16* __restrict__ Bt, __bf16* __restrict__ Cpart) {
  constexpr int KSUB = NN / SPLIT;          // 1024
  constexpr int KSTEPS = KSUB / 64;         // 16
  constexpr int LDA8 = 80;                  // fp8 bytes/row, padded
  constexpr int BN = 128;

  __shared__ unsigned char A8b[2][64 * LDA8];   // 5 KB per buffer
  __shared__ __bf16 Bb[2][128 * 64];            // 16 KB per buffer, linear

  const int t = threadIdx.x;
  const int lane = t & 63, w = t >> 6;
  const int q = lane >> 4, r16 = lane & 15;
  const int wr = w >> 1, wc = w & 1;
  const int wrow = wr * 32, wcol = wc * 64;
  const int mblk = blockIdx.x & 127, s = blockIdx.x >> 7;
  const long m0 = (long)mblk * 64, kbeg = (long)s * KSUB;

  const int srow = lane >> 3;               // row within 8-row staging chunk
  const int sccs = (lane & 7) ^ srow;       // pre-swizzled 16B chunk in source row

  const int ar = t >> 2;                    // 0..63 A8 row within tile
  const int ac4 = t & 3;                    // 16B chunk within 64B row

  auto stage_B = [&](int buf, long kb) {
#pragma unroll
    for (int i = 0; i < 4; ++i) {           // B: 16 chunks of 1KB
      const int ci = i * 4 + w;
      gload16(Bt + (long)(ci * 8 + srow) * NN + kb + sccs * 8,
              &Bb[buf][ci * 512]);
    }
  };
  auto load_A8 = [&](long kb) {
    return *(const u32x4*)(A8 + (kb >> 6) * ((long)NN * 64) + (m0 + ar) * 64 + ac4 * 16);
  };

  f32x4 acc[4][2];                          // [nt][mt]
#pragma unroll
  for (int nt = 0; nt < 4; ++nt)
#pragma unroll
    for (int mt = 0; mt < 2; ++mt) acc[nt][mt] = {0.f, 0.f, 0.f, 0.f};

  u32x4 a8c = load_A8(kbeg);
  stage_B(0, kbeg);
  *(u32x4*)&A8b[0][ar * LDA8 + ac4 * 16] = a8c;
  a8c = load_A8(kbeg + 64);

  int cur = 0;
  for (int kt = 0; kt < KSTEPS; ++kt) {
    __syncthreads();                        // buf[cur] ready (vmcnt+lgkm drain)
    if (kt + 1 < KSTEPS) {
      *(u32x4*)&A8b[cur ^ 1][ar * LDA8 + ac4 * 16] = a8c;   // loaded a phase ago
      if (kt + 2 < KSTEPS) a8c = load_A8(kbeg + (long)(kt + 2) * 64);
      stage_B(cur ^ 1, kbeg + (long)(kt + 1) * 64);
    }
#pragma unroll
    for (int ks = 0; ks < 2; ++ks) {
      bf16x8 af[2], bf[4];
#pragma unroll
      for (int mt = 0; mt < 2; ++mt) {
        u32x2 a8 = *(const u32x2*)&A8b[cur][(wrow + mt * 16 + r16) * LDA8 + ks * 32 + q * 8];
        f32x2 f;
        f = __builtin_amdgcn_cvt_pk_f32_fp8((int)a8[0], false);
        af[mt][0] = (__bf16)f[0]; af[mt][1] = (__bf16)f[1];
        f = __builtin_amdgcn_cvt_pk_f32_fp8((int)a8[0], true);
        af[mt][2] = (__bf16)f[0]; af[mt][3] = (__bf16)f[1];
        f = __builtin_amdgcn_cvt_pk_f32_fp8((int)a8[1], false);
        af[mt][4] = (__bf16)f[0]; af[mt][5] = (__bf16)f[1];
        f = __builtin_amdgcn_cvt_pk_f32_fp8((int)a8[1], true);
        af[mt][6] = (__bf16)f[0]; af[mt][7] = (__bf16)f[1];
      }
#pragma unroll
      for (int nt = 0; nt < 4; ++nt) {
        const int row = wcol + nt * 16 + r16;
        bf[nt] = *(const bf16x8*)&Bb[cur][row * 64 + ((ks * 4 + q) ^ (row & 7)) * 8];
      }
      // operand-swapped: C rows = N-dim, C cols = M-dim (values identical)
#pragma unroll
      for (int nt = 0; nt < 4; ++nt)
#pragma unroll
        for (int mt = 0; mt < 2; ++mt)
          acc[nt][mt] = __builtin_amdgcn_mfma_f32_16x16x32_bf16(bf[nt], af[mt], acc[nt][mt], 0, 0, 0);
    }
    cur ^= 1;
  }

  __bf16* Cp = Cpart + ((long)s * NN + m0) * BN;
#pragma unroll
  for (int nt = 0; nt < 4; ++nt)
#pragma unroll
    for (int mt = 0; mt < 2; ++mt) {
      const int gm = wrow + mt * 16 + r16;       // C col-side = M row
      const int gnb = wcol + nt * 16 + q * 4;    // 4 consecutive N cols
      bf16x4 ov;
#pragma unroll
      for (int r = 0; r < 4; ++r) ov[r] = (__bf16)(acc[nt][mt][r] * A_UNSCALE);
      *(bf16x4*)&Cp[(long)gm * BN + gnb] = ov;
    }
}

// ------- gemm2: epart[s] = A8tiled @ Yt^T  (swapped operands, 8B C-stores) -----
__global__ __launch_bounds__(256, 4) void k_gemm2(const unsigned char* __restrict__ A8,
    const __bf16* __restrict__ Bt, __bf16* __restrict__ Cpart) {
  constexpr int KSUB = NN / SPLIT;          // 1024
  constexpr int KSTEPS = KSUB / 64;         // 16
  constexpr int LDA8 = 80;                  // fp8 bytes/row, padded
  constexpr int BN = 64;

  __shared__ unsigned char A8b[2][64 * LDA8];   // 5 KB per buffer
  __shared__ __bf16 Bb[2][64 * 64];             // 8 KB per buffer, linear

  const int t = threadIdx.x;
  const int lane = t & 63, w = t >> 6;
  const int q = lane >> 4, r16 = lane & 15;
  const int wr = w >> 1, wc = w & 1;
  const int wrow = wr * 32, wcol = wc * 32;
  const int mblk = blockIdx.x & 127, s = blockIdx.x >> 7;
  const long m0 = (long)mblk * 64, kbeg = (long)s * KSUB;

  const int srow = lane >> 3;
  const int sccs = (lane & 7) ^ srow;

  const int ar = t >> 2;                    // 0..63 A8 row within tile
  const int ac4 = t & 3;                    // 16B chunk within 64B row

  auto stage_B = [&](int buf, long kb) {
#pragma unroll
    for (int i = 0; i < 2; ++i) {           // B: 8 chunks of 1KB
      const int ci = i * 4 + w;
      gload16(Bt + (long)(ci * 8 + srow) * NN + kb + sccs * 8,
              &Bb[buf][ci * 512]);
    }
  };
  auto load_A8 = [&](long kb) {
    return *(const u32x4*)(A8 + (kb >> 6) * ((long)NN * 64) + (m0 + ar) * 64 + ac4 * 16);
  };

  f32x4 acc[2][2];                          // [nt][mt]
#pragma unroll
  for (int nt = 0; nt < 2; ++nt)
#pragma unroll
    for (int mt = 0; mt < 2; ++mt) acc[nt][mt] = {0.f, 0.f, 0.f, 0.f};

  u32x4 a8c = load_A8(kbeg);
  stage_B(0, kbeg);
  *(u32x4*)&A8b[0][ar * LDA8 + ac4 * 16] = a8c;
  a8c = load_A8(kbeg + 64);

  int cur = 0;
  for (int kt = 0; kt < KSTEPS; ++kt) {
    __syncthreads();                        // buf[cur] ready (vmcnt+lgkm drain)
    if (kt + 1 < KSTEPS) {
      *(u32x4*)&A8b[cur ^ 1][ar * LDA8 + ac4 * 16] = a8c;   // loaded a phase ago
      if (kt + 2 < KSTEPS) a8c = load_A8(kbeg + (long)(kt + 2) * 64);
      stage_B(cur ^ 1, kbeg + (long)(kt + 1) * 64);
    }
#pragma unroll
    for (int ks = 0; ks < 2; ++ks) {
      bf16x8 af[2], bf[2];
#pragma unroll
      for (int mt = 0; mt < 2; ++mt) {
        u32x2 a8 = *(const u32x2*)&A8b[cur][(wrow + mt * 16 + r16) * LDA8 + ks * 32 + q * 8];
        f32x2 f;
        f = __builtin_amdgcn_cvt_pk_f32_fp8((int)a8[0], false);
        af[mt][0] = (__bf16)f[0]; af[mt][1] = (__bf16)f[1];
        f = __builtin_amdgcn_cvt_pk_f32_fp8((int)a8[0], true);
        af[mt][2] = (__bf16)f[0]; af[mt][3] = (__bf16)f[1];
        f = __builtin_amdgcn_cvt_pk_f32_fp8((int)a8[1], false);
        af[mt][4] = (__bf16)f[0]; af[mt][5] = (__bf16)f[1];
        f = __builtin_amdgcn_cvt_pk_f32_fp8((int)a8[1], true);
        af[mt][6] = (__bf16)f[0]; af[mt][7] = (__bf16)f[1];
      }
#pragma unroll
      for (int nt = 0; nt < 2; ++nt) {
        const int row = wcol + nt * 16 + r16;
        bf[nt] = *(const bf16x8*)&Bb[cur][row * 64 + ((ks * 4 + q) ^ (row & 7)) * 8];
      }
#pragma unroll
      for (int nt = 0; nt < 2; ++nt)
#pragma unroll
        for (int mt = 0; mt < 2; ++mt)
          acc[nt][mt] = __builtin_amdgcn_mfma_f32_16x16x32_bf16(bf[nt], af[mt], acc[nt][mt], 0, 0, 0);
    }
    cur ^= 1;
  }

  __bf16* Cp = Cpart + ((long)s * NN + m0) * BN;
#pragma unroll
  for (int nt = 0; nt < 2; ++nt)
#pragma unroll
    for (int mt = 0; mt < 2; ++mt) {
      const int gm = wrow + mt * 16 + r16;
      const int gnb = wcol + nt * 16 + q * 4;
      bf16x4 ov;
#pragma unroll
      for (int r = 0; r < 4; ++r) ov[r] = (__bf16)acc[nt][mt][r];
      *(bf16x4*)&Cp[(long)gm * BN + gnb] = ov;
    }
}

// ------- pass1: row sums of exp(-relu(dist)) over triangular block pairs -------
__global__ __launch_bounds__(256, 2) void k_pass1(const __bf16* __restrict__ emb,
    const float* __restrict__ sq, float* __restrict__ rsum) {
  constexpr int LDE = 72;
  __shared__ __bf16 Ej[128 * LDE];   // A-operand: rows of j-block
  __shared__ __bf16 Ei[128 * LDE];   // B-operand: rows of i-block (C cols)
  __shared__ float sqi[128], sqj[128], rloci[128], rlocj[128];
  const int t = threadIdx.x;
  const int p = blockIdx.x;
  int bj = (int)((sqrtf(8.f * (float)p + 1.f) - 1.f) * 0.5f);
  while ((bj + 1) * (bj + 2) / 2 <= p) ++bj;
  while (bj * (bj + 1) / 2 > p) --bj;
  const int bi = p - bj * (bj + 1) / 2;
  const bool diag = (bi == bj);
  const long i0 = (long)bi * 128, j0 = (long)bj * 128;
#pragma unroll
  for (int i = 0; i < 4; ++i) {
    int c = t + i * 256, row = c >> 3, cc = c & 7;
    *(u32x4*)&Ej[row * LDE + cc * 8] = *(const u32x4*)(emb + (j0 + row) * EMB + cc * 8);
    *(u32x4*)&Ei[row * LDE + cc * 8] = *(const u32x4*)(emb + (i0 + row) * EMB + cc * 8);
  }
  if (t < 128) { sqi[t] = sq[i0 + t]; rloci[t] = 0.f; }
  else { sqj[t - 128] = sq[j0 + t - 128]; rlocj[t - 128] = 0.f; }
  __syncthreads();

  const int lane = t & 63, w = t >> 6, q = lane >> 4, r16 = lane & 15;
  const int jr = w >> 1, ic = w & 1;   // wave tile: 64 j-rows x 64 i-cols
  f32x4 zero = {0.f, 0.f, 0.f, 0.f};
  f32x4 acc[4][4];
#pragma unroll
  for (int a = 0; a < 4; ++a)
#pragma unroll
    for (int b = 0; b < 4; ++b) acc[a][b] = zero;
#pragma unroll
  for (int ks = 0; ks < 2; ++ks) {
    bf16x8 af[4], bf[4];
#pragma unroll
    for (int jt = 0; jt < 4; ++jt)
      af[jt] = *(const bf16x8*)&Ej[(jr * 64 + jt * 16 + r16) * LDE + ks * 32 + q * 8];
#pragma unroll
    for (int it = 0; it < 4; ++it)
      bf[it] = *(const bf16x8*)&Ei[(ic * 64 + it * 16 + r16) * LDE + ks * 32 + q * 8];
#pragma unroll
    for (int jt = 0; jt < 4; ++jt)
#pragma unroll
      for (int it = 0; it < 4; ++it)
        acc[jt][it] = __builtin_amdgcn_mfma_f32_16x16x32_bf16(af[jt], bf[it], acc[jt][it], 0, 0, 0);
  }

  float colp[4] = {0.f, 0.f, 0.f, 0.f};
  float rowp[4][4];
#pragma unroll
  for (int jt = 0; jt < 4; ++jt)
#pragma unroll
    for (int r = 0; r < 4; ++r) rowp[jt][r] = 0.f;
#pragma unroll
  for (int it = 0; it < 4; ++it) {
    const int il = ic * 64 + it * 16 + r16;
    const float si = sqi[il];
#pragma unroll
    for (int jt = 0; jt < 4; ++jt)
#pragma unroll
      for (int r = 0; r < 4; ++r) {
        const int jl = jr * 64 + jt * 16 + q * 4 + r;
        float d = fmaxf(si + sqj[jl] - 2.f * acc[jt][it][r], 0.f);
        float e = __expf(-d);
        colp[it] += e;
        rowp[jt][r] += e;
      }
  }
#pragma unroll
  for (int it = 0; it < 4; ++it) {
    float pp = colp[it];
    pp += __shfl_xor(pp, 16);
    pp += __shfl_xor(pp, 32);
    if (q == 0) atomicAdd(&rloci[ic * 64 + it * 16 + r16], pp);
  }
  if (!diag) {
#pragma unroll
    for (int jt = 0; jt < 4; ++jt)
#pragma unroll
      for (int r = 0; r < 4; ++r) {
        float pp = rowp[jt][r];
        pp += __shfl_xor(pp, 1);
        pp += __shfl_xor(pp, 2);
        pp += __shfl_xor(pp, 4);
        pp += __shfl_xor(pp, 8);
        if (r16 == 0) atomicAdd(&rlocj[jr * 64 + jt * 16 + q * 4 + r], pp);
      }
  }
  __syncthreads();
  if (t < 128) {
    atomicAdd(&rsum[i0 + t], rloci[t]);
    if (!diag) atomicAdd(&rsum[j0 + t], rlocj[t]);
  }
}

// ------- pass2: out = exp(-relu(dist)) / rsum + EPS  (swapped operands) -------
// acc[nt][mt] rows = j-dim: each lane holds 4 consecutive j -> f32x4 stores.
__global__ __launch_bounds__(256, 2) void k_pass2(const __bf16* __restrict__ emb,
    const float* __restrict__ sq, const float* __restrict__ rsum,
    float* __restrict__ out) {
  constexpr int LDE = 72;
  __shared__ __bf16 Em[128 * LDE];
  __shared__ __bf16 En[128 * LDE];
  __shared__ float sqm[128], sqn[128], inv[128];
  const int t = threadIdx.x;
  const int bn = blockIdx.x & 63, bm = blockIdx.x >> 6;
  const long m0 = (long)bm * 128, n0 = (long)bn * 128;
#pragma unroll
  for (int i = 0; i < 4; ++i) {
    int c = t + i * 256, row = c >> 3, cc = c & 7;
    *(u32x4*)&Em[row * LDE + cc * 8] = *(const u32x4*)(emb + (m0 + row) * EMB + cc * 8);
    *(u32x4*)&En[row * LDE + cc * 8] = *(const u32x4*)(emb + (n0 + row) * EMB + cc * 8);
  }
  if (t < 128) { sqm[t] = sq[m0 + t]; inv[t] = 1.0f / rsum[m0 + t]; }
  else sqn[t - 128] = sq[n0 + t - 128];
  __syncthreads();

  const int lane = t & 63, w = t >> 6, q = lane >> 4, r16 = lane & 15;
  const int wr = w >> 1, wc = w & 1;
  f32x4 zero = {0.f, 0.f, 0.f, 0.f};
  f32x4 acc[4][4];                         // [nt][mt]: rows = j, cols = i
#pragma unroll
  for (int a = 0; a < 4; ++a)
#pragma unroll
    for (int b = 0; b < 4; ++b) acc[a][b] = zero;
#pragma unroll
  for (int ks = 0; ks < 2; ++ks) {
    bf16x8 am[4], an[4];
#pragma unroll
    for (int mt = 0; mt < 4; ++mt)
      am[mt] = *(const bf16x8*)&Em[(wr * 64 + mt * 16 + r16) * LDE + ks * 32 + q * 8];
#pragma unroll
    for (int nt = 0; nt < 4; ++nt)
      an[nt] = *(const bf16x8*)&En[(wc * 64 + nt * 16 + r16) * LDE + ks * 32 + q * 8];
#pragma unroll
    for (int nt = 0; nt < 4; ++nt)
#pragma unroll
      for (int mt = 0; mt < 4; ++mt)
        acc[nt][mt] = __builtin_amdgcn_mfma_f32_16x16x32_bf16(an[nt], am[mt], acc[nt][mt], 0, 0, 0);
  }
#pragma unroll
  for (int nt = 0; nt < 4; ++nt)
#pragma unroll
    for (int mt = 0; mt < 4; ++mt) {
      const int il = wr * 64 + mt * 16 + r16;       // C col-side = i row
      const int jb = wc * 64 + nt * 16 + q * 4;     // 4 consecutive j cols
      const float si = sqm[il];
      const float iv = inv[il];
      const f32x4 sj4 = *(const f32x4*)&sqn[jb];
      f32x4 ov;
#pragma unroll
      for (int r = 0; r < 4; ++r) {
        float d = fmaxf(si + sj4[r] - 2.f * acc[nt][mt][r], 0.f);
        float e = __expf(-d);
        ov[r] = fmaf(e, iv, 1e-10f);
      }
      *(f32x4*)&out[(m0 + il) * (long)NN + n0 + jb] = ov;
    }
}

extern "C" void kernel_launch(void* const* d_in, const int* in_sizes, int n_in,
                              void* d_out, int out_size, void* d_ws, size_t ws_size,
                              hipStream_t stream) {
  (void)in_sizes; (void)n_in; (void)out_size; (void)ws_size;
  const float* A  = (const float*)d_in[0];
  const float* X  = (const float*)d_in[1];
  const float* W1 = (const float*)d_in[2];
  const float* W2 = (const float*)d_in[3];
  float* out = (float*)d_out;

  char* w = (char*)d_ws;
  __bf16* hpartb = (__bf16*)w;                        // 16 MB [8][8192][128] bf16
  __bf16* epartb = (__bf16*)w;                        // reuse: 8 MB [8][8192][64]
  unsigned char* A8 = (unsigned char*)(w + (16u << 20));  // 64 MB fp8 tiled [128][8192][64]
  __bf16* xw1t  = (__bf16*)(w + (80u << 20));         // 2 MB  [128][8192]
  __bf16* ytp   = (__bf16*)(w + (82u << 20));         // 1 MB  [64][8192]
  __bf16* embb  = (__bf16*)(w + (83u << 20));         // 1 MB  [8192][64]
  float*  sq    = (float*)(w + (84u << 20));          // 32 KB
  float*  rsum  = (float*)(w + (84u << 20) + 32768);  // 32 KB

  k_qx<<<3072, 256, 0, stream>>>(A, A8, X, W1, xw1t, rsum);
  k_gemm1<<<1024, 256, 0, stream>>>(A8, xw1t, hpartb);
  k_rely<<<2048, 256, 0, stream>>>(hpartb, W2, ytp);
  k_gemm2<<<1024, 256, 0, stream>>>(A8, ytp, epartb);
  k_reduce2<<<1024, 256, 0, stream>>>(epartb, embb, sq);
  k_pass1<<<2080, 256, 0, stream>>>(embb, sq, rsum);
  k_pass2<<<4096, 256, 0, stream>>>(embb, sq, rsum, out);
}

// Round 7
// 615.180 us; speedup vs baseline: 1.0328x; 1.0328x over previous
//
#include <hip/hip_runtime.h>
#include <stdint.h>

typedef float   f32x4  __attribute__((ext_vector_type(4)));
typedef float   f32x2  __attribute__((ext_vector_type(2)));
typedef __bf16  bf16x8 __attribute__((ext_vector_type(8)));
typedef __bf16  bf16x4 __attribute__((ext_vector_type(4)));
typedef uint32_t u32x4 __attribute__((ext_vector_type(4)));
typedef uint32_t u32x2 __attribute__((ext_vector_type(2)));

#define NN 8192
#define EMB 64
#define A_SCALE 8192.0f          // A*2^13 -> [0,1): e4m3 normal range
#define A_UNSCALE (1.0f/8192.0f)
#define SPLIT 8

__device__ inline float bf16lo_f(uint32_t u) {
  uint32_t b = u << 16; float f; __builtin_memcpy(&f, &b, 4); return f;
}
__device__ inline float bf16hi_f(uint32_t u) {
  uint32_t b = u & 0xFFFF0000u; float f; __builtin_memcpy(&f, &b, 4); return f;
}

// async global->LDS, 16B per lane. LDS dest is wave-uniform base + lane*16.
__device__ inline void gload16(const void* g, void* l) {
  __builtin_amdgcn_global_load_lds(
      (const __attribute__((address_space(1))) void*)g,
      (__attribute__((address_space(3))) void*)l, 16, 0, 0);
}

// ------- quant: A fp32 -> A8 fp8 ROW-MAJOR [8192][8192], pure stream ----------
// Thread: read one f32x4 (wave reads 1KB contiguous), write one u32 (wave 256B).
// No LDS, no barriers, no strides -> should run at near copy BW.
__global__ __launch_bounds__(256) void k_quant(const float* __restrict__ A,
    unsigned char* __restrict__ A8) {
  uint32_t* A32 = (uint32_t*)A8;
  const long stride = (long)gridDim.x * 256;
  const long total = (long)NN * NN / 4;               // f32x4 units
  for (long idx = (long)blockIdx.x * 256 + threadIdx.x; idx < total; idx += stride) {
    f32x4 v = ((const f32x4*)A)[idx];
    int p8 = __builtin_amdgcn_cvt_pk_fp8_f32(v[0] * A_SCALE, v[1] * A_SCALE, 0, false);
    p8     = __builtin_amdgcn_cvt_pk_fp8_f32(v[2] * A_SCALE, v[3] * A_SCALE, p8, true);
    A32[idx] = (uint32_t)p8;
  }
}

// ------- XW1^T = (X @ W1)^T, bf16 [128][8192]; also zeroes rsum -------
__global__ __launch_bounds__(256) void k_xw1(const float* __restrict__ X,
    const float* __restrict__ W1, __bf16* __restrict__ XW1t,
    float* __restrict__ rsum) {
  if (blockIdx.x < 32) rsum[blockIdx.x * 256 + threadIdx.x] = 0.f;
  const int t = threadIdx.x;
  const int j = t & 127, r2 = t >> 7;
  const long row0 = (long)blockIdx.x * 8 + r2 * 4;   // wave-uniform 4-row group
  const f32x4* xr = (const f32x4*)(X + row0 * 256);
  float a0 = 0.f, a1 = 0.f, a2 = 0.f, a3 = 0.f;
#pragma unroll 4
  for (int k4 = 0; k4 < 64; ++k4) {
    f32x4 x0 = xr[k4];
    f32x4 x1 = xr[k4 + 64];
    f32x4 x2 = xr[k4 + 128];
    f32x4 x3 = xr[k4 + 192];
#pragma unroll
    for (int u = 0; u < 4; ++u) {
      float wv = W1[(k4 * 4 + u) * 128 + j];
      a0 += x0[u] * wv;
      a1 += x1[u] * wv;
      a2 += x2[u] * wv;
      a3 += x3[u] * wv;
    }
  }
  bf16x4 ov;
  ov[0] = (__bf16)a0; ov[1] = (__bf16)a1; ov[2] = (__bf16)a2; ov[3] = (__bf16)a3;
  *(bf16x4*)&XW1t[(long)j * NN + row0] = ov;   // row0 % 4 == 0 -> 8B aligned
}

// ------- fused: reduce split-K bf16 partials -> relu -> (row @ W2) -> Yt bf16 ----
__global__ __launch_bounds__(256) void k_rely(const __bf16* __restrict__ hp,
    const float* __restrict__ W2, __bf16* __restrict__ Yt) {
  __shared__ float hrow[4][128];
  const uint32_t* hp32 = (const uint32_t*)hp;
  const int t = threadIdx.x, lane = t & 63, w = t >> 6;
  const long row = (long)blockIdx.x * 4 + w;    // one wave == one row
  const long b32 = row * 64;                    // 128 bf16 = 64 u32 per row
  float v0 = 0.f, v1 = 0.f;
#pragma unroll
  for (int sI = 0; sI < SPLIT; ++sI) {
    uint32_t u = hp32[b32 + lane + (long)sI * 524288];
    v0 += bf16lo_f(u);
    v1 += bf16hi_f(u);
  }
  hrow[w][2 * lane]     = fmaxf(v0, 0.f);
  hrow[w][2 * lane + 1] = fmaxf(v1, 0.f);
  __syncthreads();
  float a0 = 0.f, a1 = 0.f, a2 = 0.f, a3 = 0.f;
  const f32x4* hv = (const f32x4*)&hrow[w][0];
#pragma unroll 8
  for (int c4 = 0; c4 < 32; ++c4) {
    f32x4 h = hv[c4];
    a0 += h[0] * W2[(c4 * 4 + 0) * 64 + lane];
    a1 += h[1] * W2[(c4 * 4 + 1) * 64 + lane];
    a2 += h[2] * W2[(c4 * 4 + 2) * 64 + lane];
    a3 += h[3] * W2[(c4 * 4 + 3) * 64 + lane];
  }
  Yt[(long)lane * NN + row] = (__bf16)((a0 + a1) + (a2 + a3));
}

// ------- reduce epart (bf16, scaled by 2^13) -> emb bf16 + sq ----------------
__global__ __launch_bounds__(256) void k_reduce2(const __bf16* __restrict__ ep,
    __bf16* __restrict__ embb, float* __restrict__ sq) {
  const uint32_t* ep32 = (const uint32_t*)ep;
  const int t = threadIdx.x;
  const int hl = t & 31;                              // u32 index within row
  const long row = (long)blockIdx.x * 8 + (t >> 5);   // 8 rows per block
  const long idx = row * 32 + hl;                     // 64 bf16 = 32 u32 per row
  float v0 = 0.f, v1 = 0.f;
#pragma unroll
  for (int sI = 0; sI < SPLIT; ++sI) {
    uint32_t u = ep32[idx + (long)sI * 262144];
    v0 += bf16lo_f(u);
    v1 += bf16hi_f(u);
  }
  v0 *= A_UNSCALE; v1 *= A_UNSCALE;
  __bf16 b0 = (__bf16)v0, b1 = (__bf16)v1;
  unsigned short u0, u1;
  __builtin_memcpy(&u0, &b0, 2); __builtin_memcpy(&u1, &b1, 2);
  ((uint32_t*)embb)[idx] = ((uint32_t)u1 << 16) | u0;
  float f0 = (float)b0, f1 = (float)b1;
  float s = f0 * f0 + f1 * f1;
#pragma unroll
  for (int off = 16; off >= 1; off >>= 1) s += __shfl_xor(s, off);
  if (hl == 0) sq[row] = s;
}

// ------- gemm1: hpart[s] = A8 @ XW1t^T  (fp8 A row-major, dequant at read) -----
__global__ __launch_bounds__(256, 3) void k_gemm1(const unsigned char* __restrict__ A8,
    const __bf16* __restrict__ Bt, __bf16* __restrict__ Cpart) {
  constexpr int KSUB = NN / SPLIT;          // 1024
  constexpr int KSTEPS = KSUB / 64;         // 16
  constexpr int LDA8 = 80;                  // fp8 bytes/row, padded
  constexpr int BN = 128;

  __shared__ unsigned char A8b[2][64 * LDA8];   // 5 KB per buffer
  __shared__ __bf16 Bb[2][128 * 64];            // 16 KB per buffer, linear

  const int t = threadIdx.x;
  const int lane = t & 63, w = t >> 6;
  const int q = lane >> 4, r16 = lane & 15;
  const int wr = w >> 1, wc = w & 1;
  const int wrow = wr * 32, wcol = wc * 64;
  const int mblk = blockIdx.x & 127, s = blockIdx.x >> 7;
  const long m0 = (long)mblk * 64, kbeg = (long)s * KSUB;

  const int srow = lane >> 3;               // row within 8-row staging chunk
  const int sccs = (lane & 7) ^ srow;       // pre-swizzled 16B chunk in source row

  const int ar = t >> 2;                    // 0..63 A8 row within tile
  const int ac4 = t & 3;                    // 16B chunk within 64B row

  auto stage_B = [&](int buf, long kb) {
#pragma unroll
    for (int i = 0; i < 4; ++i) {           // B: 16 chunks of 1KB
      const int ci = i * 4 + w;
      gload16(Bt + (long)(ci * 8 + srow) * NN + kb + sccs * 8,
              &Bb[buf][ci * 512]);
    }
  };
  auto load_A8 = [&](long kb) {
    return *(const u32x4*)(A8 + (m0 + ar) * (long)NN + kb + ac4 * 16);
  };

  f32x4 acc[4][2];                          // [nt][mt]
#pragma unroll
  for (int nt = 0; nt < 4; ++nt)
#pragma unroll
    for (int mt = 0; mt < 2; ++mt) acc[nt][mt] = {0.f, 0.f, 0.f, 0.f};

  u32x4 a8c = load_A8(kbeg);
  stage_B(0, kbeg);
  *(u32x4*)&A8b[0][ar * LDA8 + ac4 * 16] = a8c;
  a8c = load_A8(kbeg + 64);

  int cur = 0;
  for (int kt = 0; kt < KSTEPS; ++kt) {
    __syncthreads();                        // buf[cur] ready (vmcnt+lgkm drain)
    if (kt + 1 < KSTEPS) {
      *(u32x4*)&A8b[cur ^ 1][ar * LDA8 + ac4 * 16] = a8c;   // loaded a phase ago
      if (kt + 2 < KSTEPS) a8c = load_A8(kbeg + (long)(kt + 2) * 64);
      stage_B(cur ^ 1, kbeg + (long)(kt + 1) * 64);
    }
#pragma unroll
    for (int ks = 0; ks < 2; ++ks) {
      bf16x8 af[2], bf[4];
#pragma unroll
      for (int mt = 0; mt < 2; ++mt) {
        u32x2 a8 = *(const u32x2*)&A8b[cur][(wrow + mt * 16 + r16) * LDA8 + ks * 32 + q * 8];
        f32x2 f;
        f = __builtin_amdgcn_cvt_pk_f32_fp8((int)a8[0], false);
        af[mt][0] = (__bf16)f[0]; af[mt][1] = (__bf16)f[1];
        f = __builtin_amdgcn_cvt_pk_f32_fp8((int)a8[0], true);
        af[mt][2] = (__bf16)f[0]; af[mt][3] = (__bf16)f[1];
        f = __builtin_amdgcn_cvt_pk_f32_fp8((int)a8[1], false);
        af[mt][4] = (__bf16)f[0]; af[mt][5] = (__bf16)f[1];
        f = __builtin_amdgcn_cvt_pk_f32_fp8((int)a8[1], true);
        af[mt][6] = (__bf16)f[0]; af[mt][7] = (__bf16)f[1];
      }
#pragma unroll
      for (int nt = 0; nt < 4; ++nt) {
        const int row = wcol + nt * 16 + r16;
        bf[nt] = *(const bf16x8*)&Bb[cur][row * 64 + ((ks * 4 + q) ^ (row & 7)) * 8];
      }
      // operand-swapped: C rows = N-dim, C cols = M-dim (values identical)
#pragma unroll
      for (int nt = 0; nt < 4; ++nt)
#pragma unroll
        for (int mt = 0; mt < 2; ++mt)
          acc[nt][mt] = __builtin_amdgcn_mfma_f32_16x16x32_bf16(bf[nt], af[mt], acc[nt][mt], 0, 0, 0);
    }
    cur ^= 1;
  }

  __bf16* Cp = Cpart + ((long)s * NN + m0) * BN;
#pragma unroll
  for (int nt = 0; nt < 4; ++nt)
#pragma unroll
    for (int mt = 0; mt < 2; ++mt) {
      const int gm = wrow + mt * 16 + r16;       // C col-side = M row
      const int gnb = wcol + nt * 16 + q * 4;    // 4 consecutive N cols
      bf16x4 ov;
#pragma unroll
      for (int r = 0; r < 4; ++r) ov[r] = (__bf16)(acc[nt][mt][r] * A_UNSCALE);
      *(bf16x4*)&Cp[(long)gm * BN + gnb] = ov;
    }
}

// ------- gemm2: epart[s] = A8 @ Yt^T  (row-major A8, swapped operands) ---------
__global__ __launch_bounds__(256, 4) void k_gemm2(const unsigned char* __restrict__ A8,
    const __bf16* __restrict__ Bt, __bf16* __restrict__ Cpart) {
  constexpr int KSUB = NN / SPLIT;          // 1024
  constexpr int KSTEPS = KSUB / 64;         // 16
  constexpr int LDA8 = 80;                  // fp8 bytes/row, padded
  constexpr int BN = 64;

  __shared__ unsigned char A8b[2][64 * LDA8];   // 5 KB per buffer
  __shared__ __bf16 Bb[2][64 * 64];             // 8 KB per buffer, linear

  const int t = threadIdx.x;
  const int lane = t & 63, w = t >> 6;
  const int q = lane >> 4, r16 = lane & 15;
  const int wr = w >> 1, wc = w & 1;
  const int wrow = wr * 32, wcol = wc * 32;
  const int mblk = blockIdx.x & 127, s = blockIdx.x >> 7;
  const long m0 = (long)mblk * 64, kbeg = (long)s * KSUB;

  const int srow = lane >> 3;
  const int sccs = (lane & 7) ^ srow;

  const int ar = t >> 2;                    // 0..63 A8 row within tile
  const int ac4 = t & 3;                    // 16B chunk within 64B row

  auto stage_B = [&](int buf, long kb) {
#pragma unroll
    for (int i = 0; i < 2; ++i) {           // B: 8 chunks of 1KB
      const int ci = i * 4 + w;
      gload16(Bt + (long)(ci * 8 + srow) * NN + kb + sccs * 8,
              &Bb[buf][ci * 512]);
    }
  };
  auto load_A8 = [&](long kb) {
    return *(const u32x4*)(A8 + (m0 + ar) * (long)NN + kb + ac4 * 16);
  };

  f32x4 acc[2][2];                          // [nt][mt]
#pragma unroll
  for (int nt = 0; nt < 2; ++nt)
#pragma unroll
    for (int mt = 0; mt < 2; ++mt) acc[nt][mt] = {0.f, 0.f, 0.f, 0.f};

  u32x4 a8c = load_A8(kbeg);
  stage_B(0, kbeg);
  *(u32x4*)&A8b[0][ar * LDA8 + ac4 * 16] = a8c;
  a8c = load_A8(kbeg + 64);

  int cur = 0;
  for (int kt = 0; kt < KSTEPS; ++kt) {
    __syncthreads();                        // buf[cur] ready (vmcnt+lgkm drain)
    if (kt + 1 < KSTEPS) {
      *(u32x4*)&A8b[cur ^ 1][ar * LDA8 + ac4 * 16] = a8c;   // loaded a phase ago
      if (kt + 2 < KSTEPS) a8c = load_A8(kbeg + (long)(kt + 2) * 64);
      stage_B(cur ^ 1, kbeg + (long)(kt + 1) * 64);
    }
#pragma unroll
    for (int ks = 0; ks < 2; ++ks) {
      bf16x8 af[2], bf[2];
#pragma unroll
      for (int mt = 0; mt < 2; ++mt) {
        u32x2 a8 = *(const u32x2*)&A8b[cur][(wrow + mt * 16 + r16) * LDA8 + ks * 32 + q * 8];
        f32x2 f;
        f = __builtin_amdgcn_cvt_pk_f32_fp8((int)a8[0], false);
        af[mt][0] = (__bf16)f[0]; af[mt][1] = (__bf16)f[1];
        f = __builtin_amdgcn_cvt_pk_f32_fp8((int)a8[0], true);
        af[mt][2] = (__bf16)f[0]; af[mt][3] = (__bf16)f[1];
        f = __builtin_amdgcn_cvt_pk_f32_fp8((int)a8[1], false);
        af[mt][4] = (__bf16)f[0]; af[mt][5] = (__bf16)f[1];
        f = __builtin_amdgcn_cvt_pk_f32_fp8((int)a8[1], true);
        af[mt][6] = (__bf16)f[0]; af[mt][7] = (__bf16)f[1];
      }
#pragma unroll
      for (int nt = 0; nt < 2; ++nt) {
        const int row = wcol + nt * 16 + r16;
        bf[nt] = *(const bf16x8*)&Bb[cur][row * 64 + ((ks * 4 + q) ^ (row & 7)) * 8];
      }
#pragma unroll
      for (int nt = 0; nt < 2; ++nt)
#pragma unroll
        for (int mt = 0; mt < 2; ++mt)
          acc[nt][mt] = __builtin_amdgcn_mfma_f32_16x16x32_bf16(bf[nt], af[mt], acc[nt][mt], 0, 0, 0);
    }
    cur ^= 1;
  }

  __bf16* Cp = Cpart + ((long)s * NN + m0) * BN;
#pragma unroll
  for (int nt = 0; nt < 2; ++nt)
#pragma unroll
    for (int mt = 0; mt < 2; ++mt) {
      const int gm = wrow + mt * 16 + r16;
      const int gnb = wcol + nt * 16 + q * 4;
      bf16x4 ov;
#pragma unroll
      for (int r = 0; r < 4; ++r) ov[r] = (__bf16)acc[nt][mt][r];
      *(bf16x4*)&Cp[(long)gm * BN + gnb] = ov;
    }
}

// ------- pass1: row sums of exp(-relu(dist)) over triangular block pairs -------
__global__ __launch_bounds__(256, 2) void k_pass1(const __bf16* __restrict__ emb,
    const float* __restrict__ sq, float* __restrict__ rsum) {
  constexpr int LDE = 72;
  __shared__ __bf16 Ej[128 * LDE];   // A-operand: rows of j-block
  __shared__ __bf16 Ei[128 * LDE];   // B-operand: rows of i-block (C cols)
  __shared__ float sqi[128], sqj[128], rloci[128], rlocj[128];
  const int t = threadIdx.x;
  const int p = blockIdx.x;
  int bj = (int)((sqrtf(8.f * (float)p + 1.f) - 1.f) * 0.5f);
  while ((bj + 1) * (bj + 2) / 2 <= p) ++bj;
  while (bj * (bj + 1) / 2 > p) --bj;
  const int bi = p - bj * (bj + 1) / 2;
  const bool diag = (bi == bj);
  const long i0 = (long)bi * 128, j0 = (long)bj * 128;
#pragma unroll
  for (int i = 0; i < 4; ++i) {
    int c = t + i * 256, row = c >> 3, cc = c & 7;
    *(u32x4*)&Ej[row * LDE + cc * 8] = *(const u32x4*)(emb + (j0 + row) * EMB + cc * 8);
    *(u32x4*)&Ei[row * LDE + cc * 8] = *(const u32x4*)(emb + (i0 + row) * EMB + cc * 8);
  }
  if (t < 128) { sqi[t] = sq[i0 + t]; rloci[t] = 0.f; }
  else { sqj[t - 128] = sq[j0 + t - 128]; rlocj[t - 128] = 0.f; }
  __syncthreads();

  const int lane = t & 63, w = t >> 6, q = lane >> 4, r16 = lane & 15;
  const int jr = w >> 1, ic = w & 1;   // wave tile: 64 j-rows x 64 i-cols
  f32x4 zero = {0.f, 0.f, 0.f, 0.f};
  f32x4 acc[4][4];
#pragma unroll
  for (int a = 0; a < 4; ++a)
#pragma unroll
    for (int b = 0; b < 4; ++b) acc[a][b] = zero;
#pragma unroll
  for (int ks = 0; ks < 2; ++ks) {
    bf16x8 af[4], bf[4];
#pragma unroll
    for (int jt = 0; jt < 4; ++jt)
      af[jt] = *(const bf16x8*)&Ej[(jr * 64 + jt * 16 + r16) * LDE + ks * 32 + q * 8];
#pragma unroll
    for (int it = 0; it < 4; ++it)
      bf[it] = *(const bf16x8*)&Ei[(ic * 64 + it * 16 + r16) * LDE + ks * 32 + q * 8];
#pragma unroll
    for (int jt = 0; jt < 4; ++jt)
#pragma unroll
      for (int it = 0; it < 4; ++it)
        acc[jt][it] = __builtin_amdgcn_mfma_f32_16x16x32_bf16(af[jt], bf[it], acc[jt][it], 0, 0, 0);
  }

  float colp[4] = {0.f, 0.f, 0.f, 0.f};
  float rowp[4][4];
#pragma unroll
  for (int jt = 0; jt < 4; ++jt)
#pragma unroll
    for (int r = 0; r < 4; ++r) rowp[jt][r] = 0.f;
#pragma unroll
  for (int it = 0; it < 4; ++it) {
    const int il = ic * 64 + it * 16 + r16;
    const float si = sqi[il];
#pragma unroll
    for (int jt = 0; jt < 4; ++jt)
#pragma unroll
      for (int r = 0; r < 4; ++r) {
        const int jl = jr * 64 + jt * 16 + q * 4 + r;
        float d = fmaxf(si + sqj[jl] - 2.f * acc[jt][it][r], 0.f);
        float e = __expf(-d);
        colp[it] += e;
        rowp[jt][r] += e;
      }
  }
#pragma unroll
  for (int it = 0; it < 4; ++it) {
    float pp = colp[it];
    pp += __shfl_xor(pp, 16);
    pp += __shfl_xor(pp, 32);
    if (q == 0) atomicAdd(&rloci[ic * 64 + it * 16 + r16], pp);
  }
  if (!diag) {
#pragma unroll
    for (int jt = 0; jt < 4; ++jt)
#pragma unroll
      for (int r = 0; r < 4; ++r) {
        float pp = rowp[jt][r];
        pp += __shfl_xor(pp, 1);
        pp += __shfl_xor(pp, 2);
        pp += __shfl_xor(pp, 4);
        pp += __shfl_xor(pp, 8);
        if (r16 == 0) atomicAdd(&rlocj[jr * 64 + jt * 16 + q * 4 + r], pp);
      }
  }
  __syncthreads();
  if (t < 128) {
    atomicAdd(&rsum[i0 + t], rloci[t]);
    if (!diag) atomicAdd(&rsum[j0 + t], rlocj[t]);
  }
}

// ------- pass2: out = exp(-relu(dist)) / rsum + EPS  (swapped operands) -------
__global__ __launch_bounds__(256, 2) void k_pass2(const __bf16* __restrict__ emb,
    const float* __restrict__ sq, const float* __restrict__ rsum,
    float* __restrict__ out) {
  constexpr int LDE = 72;
  __shared__ __bf16 Em[128 * LDE];
  __shared__ __bf16 En[128 * LDE];
  __shared__ float sqm[128], sqn[128], inv[128];
  const int t = threadIdx.x;
  const int bn = blockIdx.x & 63, bm = blockIdx.x >> 6;
  const long m0 = (long)bm * 128, n0 = (long)bn * 128;
#pragma unroll
  for (int i = 0; i < 4; ++i) {
    int c = t + i * 256, row = c >> 3, cc = c & 7;
    *(u32x4*)&Em[row * LDE + cc * 8] = *(const u32x4*)(emb + (m0 + row) * EMB + cc * 8);
    *(u32x4*)&En[row * LDE + cc * 8] = *(const u32x4*)(emb + (n0 + row) * EMB + cc * 8);
  }
  if (t < 128) { sqm[t] = sq[m0 + t]; inv[t] = 1.0f / rsum[m0 + t]; }
  else sqn[t - 128] = sq[n0 + t - 128];
  __syncthreads();

  const int lane = t & 63, w = t >> 6, q = lane >> 4, r16 = lane & 15;
  const int wr = w >> 1, wc = w & 1;
  f32x4 zero = {0.f, 0.f, 0.f, 0.f};
  f32x4 acc[4][4];                         // [nt][mt]: rows = j, cols = i
#pragma unroll
  for (int a = 0; a < 4; ++a)
#pragma unroll
    for (int b = 0; b < 4; ++b) acc[a][b] = zero;
#pragma unroll
  for (int ks = 0; ks < 2; ++ks) {
    bf16x8 am[4], an[4];
#pragma unroll
    for (int mt = 0; mt < 4; ++mt)
      am[mt] = *(const bf16x8*)&Em[(wr * 64 + mt * 16 + r16) * LDE + ks * 32 + q * 8];
#pragma unroll
    for (int nt = 0; nt < 4; ++nt)
      an[nt] = *(const bf16x8*)&En[(wc * 64 + nt * 16 + r16) * LDE + ks * 32 + q * 8];
#pragma unroll
    for (int nt = 0; nt < 4; ++nt)
#pragma unroll
      for (int mt = 0; mt < 4; ++mt)
        acc[nt][mt] = __builtin_amdgcn_mfma_f32_16x16x32_bf16(an[nt], am[mt], acc[nt][mt], 0, 0, 0);
  }
#pragma unroll
  for (int nt = 0; nt < 4; ++nt)
#pragma unroll
    for (int mt = 0; mt < 4; ++mt) {
      const int il = wr * 64 + mt * 16 + r16;       // C col-side = i row
      const int jb = wc * 64 + nt * 16 + q * 4;     // 4 consecutive j cols
      const float si = sqm[il];
      const float iv = inv[il];
      const f32x4 sj4 = *(const f32x4*)&sqn[jb];
      f32x4 ov;
#pragma unroll
      for (int r = 0; r < 4; ++r) {
        float d = fmaxf(si + sj4[r] - 2.f * acc[nt][mt][r], 0.f);
        float e = __expf(-d);
        ov[r] = fmaf(e, iv, 1e-10f);
      }
      *(f32x4*)&out[(m0 + il) * (long)NN + n0 + jb] = ov;
    }
}

extern "C" void kernel_launch(void* const* d_in, const int* in_sizes, int n_in,
                              void* d_out, int out_size, void* d_ws, size_t ws_size,
                              hipStream_t stream) {
  (void)in_sizes; (void)n_in; (void)out_size; (void)ws_size;
  const float* A  = (const float*)d_in[0];
  const float* X  = (const float*)d_in[1];
  const float* W1 = (const float*)d_in[2];
  const float* W2 = (const float*)d_in[3];
  float* out = (float*)d_out;

  char* w = (char*)d_ws;
  __bf16* hpartb = (__bf16*)w;                        // 16 MB [8][8192][128] bf16
  __bf16* epartb = (__bf16*)w;                        // reuse: 8 MB [8][8192][64]
  unsigned char* A8 = (unsigned char*)(w + (16u << 20));  // 64 MB fp8 row-major [8192][8192]
  __bf16* xw1t  = (__bf16*)(w + (80u << 20));         // 2 MB  [128][8192]
  __bf16* ytp   = (__bf16*)(w + (82u << 20));         // 1 MB  [64][8192]
  __bf16* embb  = (__bf16*)(w + (83u << 20));         // 1 MB  [8192][64]
  float*  sq    = (float*)(w + (84u << 20));          // 32 KB
  float*  rsum  = (float*)(w + (84u << 20) + 32768);  // 32 KB

  k_quant<<<2048, 256, 0, stream>>>(A, A8);
  k_xw1<<<1024, 256, 0, stream>>>(X, W1, xw1t, rsum);
  k_gemm1<<<1024, 256, 0, stream>>>(A8, xw1t, hpartb);
  k_rely<<<2048, 256, 0, stream>>>(hpartb, W2, ytp);
  k_gemm2<<<1024, 256, 0, stream>>>(A8, ytp, epartb);
  k_reduce2<<<1024, 256, 0, stream>>>(epartb, embb, sq);
  k_pass1<<<2080, 256, 0, stream>>>(embb, sq, rsum);
  k_pass2<<<4096, 256, 0, stream>>>(embb, sq, rsum, out);
}